// Round 1
// baseline (1785.853 us; speedup 1.0000x reference)
//
#include <hip/hip_runtime.h>
#include <math.h>

// MHA fwd: B=2 S=2048 D=1024 H=16 HD=64. fp32 baseline (no MFMA: CDNA4 has no fp32 MFMA).
// d_out = [output (B,S,D) | attn_weights (B,H,S,S)] fp32.
// ws: q,k,v [B,H,S,HD] + attn_out [B,S,D] + rowmax/rowrecipsum -> ~67.6 MB.

#define S_  2048
#define D_  1024
#define H_  16
#define HD_ 64

#define NEG_INF (-__builtin_huge_valf())

// ---------------- GEMM: y = A @ W^T + bias (nn.Linear), 128x128x16, 256 thr, 8x8/thr ----
// MODE 0: plain store out[m*D+e]   (attn_out @ Wo^T, and x @ W^T cases)
// MODE 1: scatter to [B,H,S,HD] with *0.125 (q, folds 1/sqrt(HD) into q)
// MODE 2: scatter to [B,H,S,HD] (k, v)
template<int MODE>
__global__ __launch_bounds__(256)
void gemm_proj(const float* __restrict__ A, const float* __restrict__ W,
               const float* __restrict__ bias, float* __restrict__ out)
{
    __shared__ float As[16][132];   // [k][m], pad 132: 16B-aligned rows, write conflicts 2-way
    __shared__ float Bs[16][132];   // [k][n]
    const int t  = threadIdx.x;
    const int tx = t & 15, ty = t >> 4;
    const int m0 = blockIdx.y * 128;
    const int n0 = blockIdx.x * 128;

    float acc[8][8];
    #pragma unroll
    for (int i = 0; i < 8; ++i)
        #pragma unroll
        for (int j = 0; j < 8; ++j) acc[i][j] = 0.f;

    for (int kt = 0; kt < D_ / 16; ++kt) {
        const int k0 = kt * 16;
        #pragma unroll
        for (int rep = 0; rep < 2; ++rep) {
            const int idx = rep * 256 + t;
            const int row = idx >> 2;          // 0..127
            const int g   = (idx & 3) * 4;     // k offset within tile
            float4 a4 = *(const float4*)(A + (size_t)(m0 + row) * D_ + k0 + g);
            As[g+0][row] = a4.x; As[g+1][row] = a4.y; As[g+2][row] = a4.z; As[g+3][row] = a4.w;
            float4 b4 = *(const float4*)(W + (size_t)(n0 + row) * D_ + k0 + g);
            Bs[g+0][row] = b4.x; Bs[g+1][row] = b4.y; Bs[g+2][row] = b4.z; Bs[g+3][row] = b4.w;
        }
        __syncthreads();
        #pragma unroll
        for (int kk = 0; kk < 16; ++kk) {
            float a[8], b[8];
            *(float4*)&a[0] = *(const float4*)&As[kk][ty*8];
            *(float4*)&a[4] = *(const float4*)&As[kk][ty*8 + 4];
            *(float4*)&b[0] = *(const float4*)&Bs[kk][tx*8];
            *(float4*)&b[4] = *(const float4*)&Bs[kk][tx*8 + 4];
            #pragma unroll
            for (int i = 0; i < 8; ++i)
                #pragma unroll
                for (int j = 0; j < 8; ++j)
                    acc[i][j] = fmaf(a[i], b[j], acc[i][j]);
        }
        __syncthreads();
    }

    float bj[8];
    #pragma unroll
    for (int j = 0; j < 8; ++j) bj[j] = bias[n0 + tx*8 + j];

    #pragma unroll
    for (int i = 0; i < 8; ++i) {
        const int m = m0 + ty*8 + i;
        float o[8];
        #pragma unroll
        for (int j = 0; j < 8; ++j) {
            float v = acc[i][j] + bj[j];
            if (MODE == 1) v *= 0.125f;
            o[j] = v;
        }
        if (MODE == 0) {
            *(float4*)(out + (size_t)m * D_ + n0 + tx*8)     = *(float4*)&o[0];
            *(float4*)(out + (size_t)m * D_ + n0 + tx*8 + 4) = *(float4*)&o[4];
        } else {
            const int e0 = n0 + tx*8;                 // j-span stays inside one head (8|64)
            const int h = e0 >> 6, hd = e0 & 63;
            const int b = m >> 11, s = m & (S_ - 1);
            float* dst = out + (((size_t)(b*H_ + h) * S_ + s) * HD_ + hd);
            *(float4*)dst       = *(float4*)&o[0];
            *(float4*)(dst + 4) = *(float4*)&o[4];
        }
    }
}

// ---------------- Scores: 64x64 tiles of q @ k^T (q pre-scaled). ----------------
// kt > qt: final zeros. kt <= qt: raw scores (diag masked to -inf) into attn region.
__global__ __launch_bounds__(256)
void scores_kernel(const float* __restrict__ q, const float* __restrict__ k,
                   float* __restrict__ attn)
{
    const int kt = blockIdx.x, qt = blockIdx.y, bh = blockIdx.z;
    const int t = threadIdx.x;
    float* tile = attn + ((size_t)bh * S_ + qt*64) * S_ + kt*64;

    if (kt > qt) {
        const float4 z = make_float4(0.f, 0.f, 0.f, 0.f);
        #pragma unroll
        for (int rep = 0; rep < 4; ++rep) {
            const int idx = rep * 256 + t;
            const int row = idx >> 4, f = (idx & 15) * 4;
            *(float4*)(tile + (size_t)row * S_ + f) = z;
        }
        return;
    }

    __shared__ float qs[64][68];   // [d][row]
    __shared__ float ks[64][68];   // [d][col]
    const float* qg = q + ((size_t)bh * S_ + qt*64) * HD_;
    const float* kg = k + ((size_t)bh * S_ + kt*64) * HD_;
    #pragma unroll
    for (int rep = 0; rep < 4; ++rep) {
        const int idx = rep * 256 + t;
        const int row = idx >> 4, g = (idx & 15) * 4;
        float4 a4 = *(const float4*)(qg + row * HD_ + g);
        qs[g+0][row] = a4.x; qs[g+1][row] = a4.y; qs[g+2][row] = a4.z; qs[g+3][row] = a4.w;
        float4 b4 = *(const float4*)(kg + row * HD_ + g);
        ks[g+0][row] = b4.x; ks[g+1][row] = b4.y; ks[g+2][row] = b4.z; ks[g+3][row] = b4.w;
    }
    __syncthreads();

    const int tx = t & 15, ty = t >> 4;
    const int r0 = ty * 4, c0 = tx * 4;
    float acc[4][4] = {};
    #pragma unroll
    for (int d = 0; d < 64; ++d) {
        float4 a4 = *(const float4*)&qs[d][r0];
        float4 b4 = *(const float4*)&ks[d][c0];
        const float a[4] = {a4.x, a4.y, a4.z, a4.w};
        const float b[4] = {b4.x, b4.y, b4.z, b4.w};
        #pragma unroll
        for (int i = 0; i < 4; ++i)
            #pragma unroll
            for (int j = 0; j < 4; ++j)
                acc[i][j] = fmaf(a[i], b[j], acc[i][j]);
    }
    #pragma unroll
    for (int i = 0; i < 4; ++i) {
        float o[4];
        #pragma unroll
        for (int j = 0; j < 4; ++j) {
            float vv = acc[i][j];
            if (kt == qt && (c0 + j) > (r0 + i)) vv = NEG_INF;  // causal mask on diagonal tile
            o[j] = vv;
        }
        *(float4*)(tile + (size_t)(r0 + i) * S_ + c0) = *(float4*)&o[0];
    }
}

// ---------------- Row stats: m = rowmax, store m and 1/sumexp. 4 lanes per row. ------
__global__ __launch_bounds__(256)
void stats_kernel(const float* __restrict__ attn,
                  float* __restrict__ mrow, float* __restrict__ lrow)
{
    const int tg  = blockIdx.x * 256 + threadIdx.x;
    const int row = tg >> 2, g = tg & 3;       // row in [0, B*H*S)
    const int bh  = row >> 11, s = row & (S_ - 1);
    const float* sr = attn + ((size_t)bh * S_ + s) * S_;
    float m = NEG_INF, l = 0.f;
    for (int kk = g; kk <= s; kk += 4) {       // only valid (k<=s) entries
        const float x = sr[kk];
        if (x > m) { l *= __expf(m - x); m = x; }
        l += __expf(x - m);
    }
    #pragma unroll
    for (int off = 1; off < 4; off <<= 1) {
        const float mo = __shfl_xor(m, off, 4);
        const float lo = __shfl_xor(l, off, 4);
        const float mn = fmaxf(m, mo);
        const float e1 = (m  == mn) ? 1.f : __expf(m  - mn);  // guards -inf - -inf = nan
        const float e2 = (mo == mn) ? 1.f : __expf(mo - mn);
        l = l * e1 + lo * e2;
        m = mn;
    }
    if (g == 0) { mrow[row] = m; lrow[row] = 1.f / l; }
}

// ---------------- Weights (in-place softmax write) + PV GEMM. per (qt, bh). ----------
__global__ __launch_bounds__(256)
void wpv_kernel(const float* __restrict__ v, float* __restrict__ attn,
                const float* __restrict__ mrow, const float* __restrict__ lrow,
                float* __restrict__ ao)
{
    const int qt = blockIdx.x, bh = blockIdx.y;
    const int t = threadIdx.x;
    __shared__ float ws_[32][68];   // [k][row] softmaxed weights
    __shared__ float vs[32][68];    // [k][d]
    __shared__ float ms[64], rls[64];
    if (t < 64) {
        ms[t]  = mrow[bh * S_ + qt*64 + t];
        rls[t] = lrow[bh * S_ + qt*64 + t];
    }
    __syncthreads();

    const int tx = t & 15, ty = t >> 4;
    const int r0 = ty * 4, c0 = tx * 4;
    float acc[4][4] = {};
    float* arow = attn + ((size_t)bh * S_ + qt*64) * S_;
    const float* vg = v + (size_t)bh * S_ * HD_;
    const int nk = (qt + 1) * 2;   // 32-wide k subtiles up to end of diagonal tile

    for (int kt = 0; kt < nk; ++kt) {
        const int kbase = kt * 32;
        #pragma unroll
        for (int rep = 0; rep < 2; ++rep) {    // stage scores -> weights (write back) + LDS^T
            const int idx = rep * 256 + t;
            const int row = idx >> 3, u = (idx & 7) * 4;
            float* gp = arow + (size_t)row * S_ + kbase + u;
            float4 s4 = *(float4*)gp;
            const float mm = ms[row], rl = rls[row];
            float4 w4;
            w4.x = __expf(s4.x - mm) * rl;     // -inf scores -> exactly 0
            w4.y = __expf(s4.y - mm) * rl;
            w4.z = __expf(s4.z - mm) * rl;
            w4.w = __expf(s4.w - mm) * rl;
            *(float4*)gp = w4;                 // final attn_weights output
            ws_[u+0][row] = w4.x; ws_[u+1][row] = w4.y; ws_[u+2][row] = w4.z; ws_[u+3][row] = w4.w;
        }
        #pragma unroll
        for (int rep = 0; rep < 2; ++rep) {    // stage v
            const int idx = rep * 256 + t;
            const int kk = idx >> 4, f = (idx & 15) * 4;
            *(float4*)&vs[kk][f] = *(const float4*)(vg + (size_t)(kbase + kk) * HD_ + f);
        }
        __syncthreads();
        #pragma unroll
        for (int kk = 0; kk < 32; ++kk) {
            float4 w4 = *(const float4*)&ws_[kk][r0];
            float4 v4 = *(const float4*)&vs[kk][c0];
            const float w[4]  = {w4.x, w4.y, w4.z, w4.w};
            const float vv[4] = {v4.x, v4.y, v4.z, v4.w};
            #pragma unroll
            for (int i = 0; i < 4; ++i)
                #pragma unroll
                for (int j = 0; j < 4; ++j)
                    acc[i][j] = fmaf(w[i], vv[j], acc[i][j]);
        }
        __syncthreads();
    }

    const int b = bh >> 4, h = bh & 15;
    #pragma unroll
    for (int i = 0; i < 4; ++i) {
        const int s = qt*64 + r0 + i;
        *(float4*)(ao + ((size_t)(b * S_ + s)) * D_ + h * HD_ + c0) = *(float4*)&acc[i][0];
    }
}

extern "C" void kernel_launch(void* const* d_in, const int* in_sizes, int n_in,
                              void* d_out, int out_size, void* d_ws, size_t ws_size,
                              hipStream_t stream)
{
    const float* x  = (const float*)d_in[0];
    const float* Wq = (const float*)d_in[1];
    const float* bq = (const float*)d_in[2];
    const float* Wk = (const float*)d_in[3];
    const float* bk = (const float*)d_in[4];
    const float* Wv = (const float*)d_in[5];
    const float* bv = (const float*)d_in[6];
    const float* Wo = (const float*)d_in[7];
    const float* bo = (const float*)d_in[8];

    float* out  = (float*)d_out;
    float* attn = out + (size_t)2 * S_ * D_;          // 4,194,304 floats offset

    float* ws   = (float*)d_ws;                        // needs ~67.6 MB
    float* q    = ws;
    float* k    = ws + (size_t)4194304;
    float* v    = ws + (size_t)8388608;
    float* ao   = ws + (size_t)12582912;
    float* mrow = ws + (size_t)16777216;
    float* lrow = mrow + 65536;

    const dim3 gg(8, 32);   // N/128, M/128
    gemm_proj<1><<<gg, 256, 0, stream>>>(x, Wq, bq, q);   // q, pre-scaled by 1/8
    gemm_proj<2><<<gg, 256, 0, stream>>>(x, Wk, bk, k);
    gemm_proj<2><<<gg, 256, 0, stream>>>(x, Wv, bv, v);
    scores_kernel<<<dim3(32, 32, 32), 256, 0, stream>>>(q, k, attn);
    stats_kernel<<<1024, 256, 0, stream>>>(attn, mrow, lrow);
    wpv_kernel<<<dim3(32, 32), 256, 0, stream>>>(v, attn, mrow, lrow, ao);
    gemm_proj<0><<<gg, 256, 0, stream>>>(ao, Wo, bo, out);
}

// Round 3
// 938.598 us; speedup vs baseline: 1.9027x; 1.9027x over previous
//
#include <hip/hip_runtime.h>
#include <math.h>

// MHA fwd, MI355X. B=2 S=2048 D=1024 H=16 HD=64.
// Strategy: all GEMM-shaped compute on MFMA via 2-term bf16 split
// (x = hi + lo; x*y ~= hi*hi + hi*lo + lo*hi, rel err ~2^-17 ~ fp32).
// Pipeline: qkv_gemm (split-bf16 out) -> attn_fused (2-pass online softmax,
// writes attn_weights + pre-split O) -> o_gemm.
// ws: q,k,v,o as hi/lo bf16 arrays: 8 * 4,194,304 * 2B = 64 MB.
// R2 fix: attn_fused LDS tiles were [64][40] (stride for BK=32) but head dim
// is 64 -> rows overflowed into each other. Now [64][72].

#define S_ 2048
#define D_ 1024

typedef __attribute__((ext_vector_type(8))) short bf16x8;
typedef __attribute__((ext_vector_type(4))) float f32x4;
typedef unsigned short u16;
typedef unsigned int u32;

#define MFMA(a, b, c) __builtin_amdgcn_mfma_f32_16x16x32_bf16((a), (b), (c), 0, 0, 0)

__device__ __forceinline__ u16 bf16rne(float f) {
    u32 u = __float_as_uint(f);
    u32 r = u + 0x7FFFu + ((u >> 16) & 1u);
    return (u16)(r >> 16);
}
__device__ __forceinline__ float bf16tof(u16 h) {
    return __uint_as_float(((u32)h) << 16);
}
__device__ __forceinline__ void split2(float f, u16& hi, u16& lo) {
    hi = bf16rne(f);
    lo = bf16rne(f - bf16tof(hi));
}
// split 8 floats (two float4) into packed hi (uint4 = 8 bf16) and lo
__device__ __forceinline__ void split8(const float4 a, const float4 b, uint4& hi, uint4& lo) {
    u16 h0,h1,h2,h3,h4,h5,h6,h7, l0,l1,l2,l3,l4,l5,l6,l7;
    split2(a.x,h0,l0); split2(a.y,h1,l1); split2(a.z,h2,l2); split2(a.w,h3,l3);
    split2(b.x,h4,l4); split2(b.y,h5,l5); split2(b.z,h6,l6); split2(b.w,h7,l7);
    hi.x = (u32)h0 | ((u32)h1 << 16); hi.y = (u32)h2 | ((u32)h3 << 16);
    hi.z = (u32)h4 | ((u32)h5 << 16); hi.w = (u32)h6 | ((u32)h7 << 16);
    lo.x = (u32)l0 | ((u32)l1 << 16); lo.y = (u32)l2 | ((u32)l3 << 16);
    lo.z = (u32)l4 | ((u32)l5 << 16); lo.w = (u32)l6 | ((u32)l7 << 16);
}

// ============ QKV projection: y = x @ W^T + b, MFMA split-bf16 ============
// tile 128(M) x 64(N), BK=32, 256 thr = 4 waves (2x2), wave tile 64x32.
// z selects (Wq,bq,q)/(Wk,bk,k)/(Wv,bv,v). q pre-scaled by 0.125.
// dst layout: [b][h][s][hd] as separate hi/lo bf16 arrays.
__global__ __launch_bounds__(256, 2)
void qkv_gemm(const float* __restrict__ x,
              const float* __restrict__ Wq, const float* __restrict__ bq,
              const float* __restrict__ Wk, const float* __restrict__ bk,
              const float* __restrict__ Wv, const float* __restrict__ bv,
              u16* __restrict__ q_hi, u16* __restrict__ q_lo,
              u16* __restrict__ k_hi, u16* __restrict__ k_lo,
              u16* __restrict__ v_hi, u16* __restrict__ v_lo)
{
    __shared__ u16 sAh[128][40], sAl[128][40];   // [m][k], BK=32 + pad
    __shared__ u16 sBh[64][40],  sBl[64][40];    // [n][k]

    const int t = threadIdx.x;
    const int z = blockIdx.z;
    const float* W    = (z == 0) ? Wq : (z == 1) ? Wk : Wv;
    const float* bias = (z == 0) ? bq : (z == 1) ? bk : bv;
    u16* dhi = (z == 0) ? q_hi : (z == 1) ? k_hi : v_hi;
    u16* dlo = (z == 0) ? q_lo : (z == 1) ? k_lo : v_lo;
    const int n0 = blockIdx.x * 64;
    const int m0 = blockIdx.y * 128;

    const int wid = t >> 6, lane = t & 63, lr = lane & 15, lh = lane >> 4;
    const int wm = wid >> 1, wn = wid & 1;

    f32x4 acc[4][2];
    #pragma unroll
    for (int i = 0; i < 4; ++i)
        #pragma unroll
        for (int j = 0; j < 2; ++j) acc[i][j] = (f32x4){0.f, 0.f, 0.f, 0.f};

    const int ar = t >> 1, ac = (t & 1) * 16;   // A stage: 16 fp32 per thread
    const int br = t >> 2, bc = (t & 3) * 8;    // B stage: 8 fp32 per thread

    for (int kt = 0; kt < 1024; kt += 32) {
        {   // stage A (x, fp32 -> split bf16)
            const float* src = x + (size_t)(m0 + ar) * 1024 + kt + ac;
            float4 f0 = *(const float4*)(src);
            float4 f1 = *(const float4*)(src + 4);
            float4 f2 = *(const float4*)(src + 8);
            float4 f3 = *(const float4*)(src + 12);
            uint4 h4, l4;
            split8(f0, f1, h4, l4);
            *(uint4*)&sAh[ar][ac] = h4;  *(uint4*)&sAl[ar][ac] = l4;
            split8(f2, f3, h4, l4);
            *(uint4*)&sAh[ar][ac + 8] = h4;  *(uint4*)&sAl[ar][ac + 8] = l4;
        }
        {   // stage B (W rows = out features)
            const float* src = W + (size_t)(n0 + br) * 1024 + kt + bc;
            float4 f0 = *(const float4*)(src);
            float4 f1 = *(const float4*)(src + 4);
            uint4 h4, l4;
            split8(f0, f1, h4, l4);
            *(uint4*)&sBh[br][bc] = h4;  *(uint4*)&sBl[br][bc] = l4;
        }
        __syncthreads();

        bf16x8 ah[4], al[4], bh[2], bl[2];
        #pragma unroll
        for (int i = 0; i < 4; ++i) {
            ah[i] = *(const bf16x8*)&sAh[wm*64 + i*16 + lr][lh*8];
            al[i] = *(const bf16x8*)&sAl[wm*64 + i*16 + lr][lh*8];
        }
        #pragma unroll
        for (int j = 0; j < 2; ++j) {
            bh[j] = *(const bf16x8*)&sBh[wn*32 + j*16 + lr][lh*8];
            bl[j] = *(const bf16x8*)&sBl[wn*32 + j*16 + lr][lh*8];
        }
        #pragma unroll
        for (int i = 0; i < 4; ++i)
            #pragma unroll
            for (int j = 0; j < 2; ++j) {
                acc[i][j] = MFMA(ah[i], bh[j], acc[i][j]);
                acc[i][j] = MFMA(ah[i], bl[j], acc[i][j]);
                acc[i][j] = MFMA(al[i], bh[j], acc[i][j]);
            }
        __syncthreads();
    }

    #pragma unroll
    for (int j = 0; j < 2; ++j) {
        const int n = n0 + wn*32 + j*16 + lr;
        const float bj = bias[n];
        const int h = n >> 6, hd = n & 63;
        #pragma unroll
        for (int i = 0; i < 4; ++i)
            #pragma unroll
            for (int r = 0; r < 4; ++r) {
                const int m = m0 + wm*64 + i*16 + lh*4 + r;
                float val = acc[i][j][r] + bj;
                if (z == 0) val *= 0.125f;            // fold 1/sqrt(64) into q
                u16 vh, vl; split2(val, vh, vl);
                const int b = m >> 11, s = m & 2047;
                const size_t off = (((size_t)(b*16 + h))*2048 + s)*64 + hd;
                dhi[off] = vh;  dlo[off] = vl;
            }
    }
}

// ============ Fused attention per (qt, bh): 64 q-rows ============
// pass1: S^T = mfma(K,Q) -> online rowmax/sumexp (q lane-local).
// pass2: S = mfma(Q,K) -> weights (write global + LDS) -> PV via mfma(W,V).
__global__ __launch_bounds__(256, 2)
void attn_fused(const u16* __restrict__ q_hi, const u16* __restrict__ q_lo,
                const u16* __restrict__ k_hi, const u16* __restrict__ k_lo,
                const u16* __restrict__ v_hi, const u16* __restrict__ v_lo,
                float* __restrict__ attn,
                u16* __restrict__ o_hi, u16* __restrict__ o_lo)
{
    __shared__ u16 sQh[64][72], sQl[64][72];   // [row][d], d=64 + 8 pad
    __shared__ u16 sKh[64][72], sKl[64][72];   // [row][d]
    __shared__ u16 sVh[64][72], sVl[64][72];   // transposed: [d][kv]
    __shared__ float sW[64][68];               // fp32 weights tile [q][k]
    __shared__ float sM[64], sL[64];

    const int t = threadIdx.x;
    const int qt = blockIdx.x, bh = blockIdx.y;
    const int wid = t >> 6, lane = t & 63, lr = lane & 15, lh = lane >> 4;

    const size_t qkvbase = (size_t)bh * 2048 * 64;
    const int sr = t >> 2, sc = (t & 3) * 16;   // 16 bf16 per thread per array

    {   // stage Q tile (once)
        const u16* s1 = q_hi + qkvbase + (size_t)(qt*64 + sr)*64 + sc;
        *(uint4*)&sQh[sr][sc]     = *(const uint4*)s1;
        *(uint4*)&sQh[sr][sc + 8] = *(const uint4*)(s1 + 8);
        const u16* s2 = q_lo + qkvbase + (size_t)(qt*64 + sr)*64 + sc;
        *(uint4*)&sQl[sr][sc]     = *(const uint4*)s2;
        *(uint4*)&sQl[sr][sc + 8] = *(const uint4*)(s2 + 8);
    }
    __syncthreads();

    bf16x8 qfh[2], qfl[2];   // this wave's q-strip frags (rows wid*16..+15)
    #pragma unroll
    for (int d = 0; d < 2; ++d) {
        qfh[d] = *(const bf16x8*)&sQh[wid*16 + lr][d*32 + lh*8];
        qfl[d] = *(const bf16x8*)&sQl[wid*16 + lr][d*32 + lh*8];
    }

    // ---- pass 1: online stats. lane's q-col = qt*64 + wid*16 + lr ----
    float m = -1e30f, l = 0.f;
    const int qg1 = qt*64 + wid*16 + lr;
    for (int kt = 0; kt <= qt; ++kt) {
        const u16* s1 = k_hi + qkvbase + (size_t)(kt*64 + sr)*64 + sc;
        *(uint4*)&sKh[sr][sc]     = *(const uint4*)s1;
        *(uint4*)&sKh[sr][sc + 8] = *(const uint4*)(s1 + 8);
        const u16* s2 = k_lo + qkvbase + (size_t)(kt*64 + sr)*64 + sc;
        *(uint4*)&sKl[sr][sc]     = *(const uint4*)s2;
        *(uint4*)&sKl[sr][sc + 8] = *(const uint4*)(s2 + 8);
        __syncthreads();

        f32x4 st[4];
        #pragma unroll
        for (int s = 0; s < 4; ++s) st[s] = (f32x4){0.f, 0.f, 0.f, 0.f};
        #pragma unroll
        for (int d = 0; d < 2; ++d)
            #pragma unroll
            for (int s = 0; s < 4; ++s) {
                bf16x8 kfh = *(const bf16x8*)&sKh[s*16 + lr][d*32 + lh*8];
                bf16x8 kfl = *(const bf16x8*)&sKl[s*16 + lr][d*32 + lh*8];
                st[s] = MFMA(kfh, qfh[d], st[s]);   // S^T[k][q]
                st[s] = MFMA(kfh, qfl[d], st[s]);
                st[s] = MFMA(kfl, qfh[d], st[s]);
            }
        if (kt == qt) {   // causal mask on diagonal tile (k > q -> -1e30)
            #pragma unroll
            for (int s = 0; s < 4; ++s)
                #pragma unroll
                for (int r = 0; r < 4; ++r) {
                    const int kg = kt*64 + s*16 + lh*4 + r;
                    if (kg > qg1) st[s][r] = -1e30f;
                }
        }
        float pm = -1e30f;
        #pragma unroll
        for (int s = 0; s < 4; ++s)
            #pragma unroll
            for (int r = 0; r < 4; ++r) pm = fmaxf(pm, st[s][r]);
        pm = fmaxf(pm, __shfl_xor(pm, 16));
        pm = fmaxf(pm, __shfl_xor(pm, 32));
        float pl = 0.f;
        #pragma unroll
        for (int s = 0; s < 4; ++s)
            #pragma unroll
            for (int r = 0; r < 4; ++r) pl += __expf(st[s][r] - pm);
        pl += __shfl_xor(pl, 16);
        pl += __shfl_xor(pl, 32);
        const float mn = fmaxf(m, pm);
        l = l * __expf(m - mn) + pl * __expf(pm - mn);
        m = mn;
        __syncthreads();
    }
    if (lh == 0) { sM[wid*16 + lr] = m; sL[wid*16 + lr] = 1.f / l; }
    __syncthreads();

    // ---- pass 2: weights + PV. lane's q-rows = qt*64 + wid*16 + lh*4 + r ----
    float mr[4], rl[4];
    #pragma unroll
    for (int r = 0; r < 4; ++r) {
        mr[r] = sM[wid*16 + lh*4 + r];
        rl[r] = sL[wid*16 + lh*4 + r];
    }
    f32x4 oacc[4];
    #pragma unroll
    for (int ds = 0; ds < 4; ++ds) oacc[ds] = (f32x4){0.f, 0.f, 0.f, 0.f};

    float* aw = attn + (size_t)bh * 2048 * 2048;
    const int vk = t & 63, vd = (t >> 6) * 16;   // V transpose-stage mapping

    for (int kt = 0; kt < 32; ++kt) {
        if (kt <= qt) {
            {   // stage K
                const u16* s1 = k_hi + qkvbase + (size_t)(kt*64 + sr)*64 + sc;
                *(uint4*)&sKh[sr][sc]     = *(const uint4*)s1;
                *(uint4*)&sKh[sr][sc + 8] = *(const uint4*)(s1 + 8);
                const u16* s2 = k_lo + qkvbase + (size_t)(kt*64 + sr)*64 + sc;
                *(uint4*)&sKl[sr][sc]     = *(const uint4*)s2;
                *(uint4*)&sKl[sr][sc + 8] = *(const uint4*)(s2 + 8);
            }
            {   // stage V transposed: sV[d][k]
                const u16* vs = v_hi + qkvbase + (size_t)(kt*64 + vk)*64 + vd;
                uint4 A = *(const uint4*)vs, B = *(const uint4*)(vs + 8);
                sVh[vd+ 0][vk] = (u16)(A.x & 0xFFFF); sVh[vd+ 1][vk] = (u16)(A.x >> 16);
                sVh[vd+ 2][vk] = (u16)(A.y & 0xFFFF); sVh[vd+ 3][vk] = (u16)(A.y >> 16);
                sVh[vd+ 4][vk] = (u16)(A.z & 0xFFFF); sVh[vd+ 5][vk] = (u16)(A.z >> 16);
                sVh[vd+ 6][vk] = (u16)(A.w & 0xFFFF); sVh[vd+ 7][vk] = (u16)(A.w >> 16);
                sVh[vd+ 8][vk] = (u16)(B.x & 0xFFFF); sVh[vd+ 9][vk] = (u16)(B.x >> 16);
                sVh[vd+10][vk] = (u16)(B.y & 0xFFFF); sVh[vd+11][vk] = (u16)(B.y >> 16);
                sVh[vd+12][vk] = (u16)(B.z & 0xFFFF); sVh[vd+13][vk] = (u16)(B.z >> 16);
                sVh[vd+14][vk] = (u16)(B.w & 0xFFFF); sVh[vd+15][vk] = (u16)(B.w >> 16);
                const u16* vs2 = v_lo + qkvbase + (size_t)(kt*64 + vk)*64 + vd;
                A = *(const uint4*)vs2; B = *(const uint4*)(vs2 + 8);
                sVl[vd+ 0][vk] = (u16)(A.x & 0xFFFF); sVl[vd+ 1][vk] = (u16)(A.x >> 16);
                sVl[vd+ 2][vk] = (u16)(A.y & 0xFFFF); sVl[vd+ 3][vk] = (u16)(A.y >> 16);
                sVl[vd+ 4][vk] = (u16)(A.z & 0xFFFF); sVl[vd+ 5][vk] = (u16)(A.z >> 16);
                sVl[vd+ 6][vk] = (u16)(A.w & 0xFFFF); sVl[vd+ 7][vk] = (u16)(A.w >> 16);
                sVl[vd+ 8][vk] = (u16)(B.x & 0xFFFF); sVl[vd+ 9][vk] = (u16)(B.x >> 16);
                sVl[vd+10][vk] = (u16)(B.y & 0xFFFF); sVl[vd+11][vk] = (u16)(B.y >> 16);
                sVl[vd+12][vk] = (u16)(B.z & 0xFFFF); sVl[vd+13][vk] = (u16)(B.z >> 16);
                sVl[vd+14][vk] = (u16)(B.w & 0xFFFF); sVl[vd+15][vk] = (u16)(B.w >> 16);
            }
            __syncthreads();

            f32x4 st[4];
            #pragma unroll
            for (int s = 0; s < 4; ++s) st[s] = (f32x4){0.f, 0.f, 0.f, 0.f};
            #pragma unroll
            for (int d = 0; d < 2; ++d)
                #pragma unroll
                for (int s = 0; s < 4; ++s) {
                    bf16x8 kfh = *(const bf16x8*)&sKh[s*16 + lr][d*32 + lh*8];
                    bf16x8 kfl = *(const bf16x8*)&sKl[s*16 + lr][d*32 + lh*8];
                    st[s] = MFMA(qfh[d], kfh, st[s]);   // S[q][k]
                    st[s] = MFMA(qfh[d], kfl, st[s]);
                    st[s] = MFMA(qfl[d], kfh, st[s]);
                }
            // weights: write to global (output!) and to sW for PV
            #pragma unroll
            for (int s = 0; s < 4; ++s)
                #pragma unroll
                for (int r = 0; r < 4; ++r) {
                    const int qrow = wid*16 + lh*4 + r;        // local 0..63
                    const int kg = kt*64 + s*16 + lr;
                    float w;
                    if (kt == qt && kg > qt*64 + qrow) w = 0.f;
                    else w = __expf(st[s][r] - mr[r]) * rl[r];
                    aw[(size_t)(qt*64 + qrow)*2048 + kg] = w;
                    sW[qrow][s*16 + lr] = w;
                }
            __syncthreads();
            // PV: A = weights strip (rows wid*16..+15), B = V (via sV[d][k])
            #pragma unroll
            for (int ks = 0; ks < 2; ++ks) {
                float4 w0 = *(const float4*)&sW[wid*16 + lr][ks*32 + lh*8];
                float4 w1 = *(const float4*)&sW[wid*16 + lr][ks*32 + lh*8 + 4];
                uint4 h4, l4;
                split8(w0, w1, h4, l4);
                bf16x8 wfh, wfl;
                wfh[0] = (short)(h4.x & 0xFFFF); wfh[1] = (short)(h4.x >> 16);
                wfh[2] = (short)(h4.y & 0xFFFF); wfh[3] = (short)(h4.y >> 16);
                wfh[4] = (short)(h4.z & 0xFFFF); wfh[5] = (short)(h4.z >> 16);
                wfh[6] = (short)(h4.w & 0xFFFF); wfh[7] = (short)(h4.w >> 16);
                wfl[0] = (short)(l4.x & 0xFFFF); wfl[1] = (short)(l4.x >> 16);
                wfl[2] = (short)(l4.y & 0xFFFF); wfl[3] = (short)(l4.y >> 16);
                wfl[4] = (short)(l4.z & 0xFFFF); wfl[5] = (short)(l4.z >> 16);
                wfl[6] = (short)(l4.w & 0xFFFF); wfl[7] = (short)(l4.w >> 16);
                #pragma unroll
                for (int ds = 0; ds < 4; ++ds) {
                    bf16x8 vfh = *(const bf16x8*)&sVh[ds*16 + lr][ks*32 + lh*8];
                    bf16x8 vfl = *(const bf16x8*)&sVl[ds*16 + lr][ks*32 + lh*8];
                    oacc[ds] = MFMA(wfh, vfh, oacc[ds]);
                    oacc[ds] = MFMA(wfh, vfl, oacc[ds]);
                    oacc[ds] = MFMA(wfl, vfh, oacc[ds]);
                }
            }
            __syncthreads();
        } else {   // upper-triangle tiles: final zeros (uniform branch, no barriers)
            #pragma unroll
            for (int s = 0; s < 4; ++s)
                #pragma unroll
                for (int r = 0; r < 4; ++r)
                    aw[(size_t)(qt*64 + wid*16 + lh*4 + r)*2048 + kt*64 + s*16 + lr] = 0.f;
        }
    }

    // epilogue: O -> pre-split bf16 [b][s][1024]
    const int b = bh >> 4, hh = bh & 15;
    #pragma unroll
    for (int ds = 0; ds < 4; ++ds)
        #pragma unroll
        for (int r = 0; r < 4; ++r) {
            const int qrow = qt*64 + wid*16 + lh*4 + r;
            const size_t off = ((size_t)(b*2048 + qrow))*1024 + hh*64 + ds*16 + lr;
            u16 vh, vl; split2(oacc[ds][r], vh, vl);
            o_hi[off] = vh;  o_lo[off] = vl;
        }
}

// ============ Output projection: out = O @ Wo^T + bo (fp32 out) ============
__global__ __launch_bounds__(256, 2)
void o_gemm(const u16* __restrict__ a_hi, const u16* __restrict__ a_lo,
            const float* __restrict__ Wo, const float* __restrict__ bo,
            float* __restrict__ out)
{
    __shared__ u16 sAh[128][40], sAl[128][40];
    __shared__ u16 sBh[64][40],  sBl[64][40];

    const int t = threadIdx.x;
    const int n0 = blockIdx.x * 64;
    const int m0 = blockIdx.y * 128;
    const int wid = t >> 6, lane = t & 63, lr = lane & 15, lh = lane >> 4;
    const int wm = wid >> 1, wn = wid & 1;

    f32x4 acc[4][2];
    #pragma unroll
    for (int i = 0; i < 4; ++i)
        #pragma unroll
        for (int j = 0; j < 2; ++j) acc[i][j] = (f32x4){0.f, 0.f, 0.f, 0.f};

    const int ar = t >> 1, ac = (t & 1) * 16;
    const int br = t >> 2, bc = (t & 3) * 8;

    for (int kt = 0; kt < 1024; kt += 32) {
        {   // stage A: already-split bf16, pure copy
            const u16* s1 = a_hi + (size_t)(m0 + ar) * 1024 + kt + ac;
            *(uint4*)&sAh[ar][ac]     = *(const uint4*)s1;
            *(uint4*)&sAh[ar][ac + 8] = *(const uint4*)(s1 + 8);
            const u16* s2 = a_lo + (size_t)(m0 + ar) * 1024 + kt + ac;
            *(uint4*)&sAl[ar][ac]     = *(const uint4*)s2;
            *(uint4*)&sAl[ar][ac + 8] = *(const uint4*)(s2 + 8);
        }
        {   // stage B: Wo fp32 -> split
            const float* src = Wo + (size_t)(n0 + br) * 1024 + kt + bc;
            float4 f0 = *(const float4*)(src);
            float4 f1 = *(const float4*)(src + 4);
            uint4 h4, l4;
            split8(f0, f1, h4, l4);
            *(uint4*)&sBh[br][bc] = h4;  *(uint4*)&sBl[br][bc] = l4;
        }
        __syncthreads();

        bf16x8 ah[4], al[4], bh[2], bl[2];
        #pragma unroll
        for (int i = 0; i < 4; ++i) {
            ah[i] = *(const bf16x8*)&sAh[wm*64 + i*16 + lr][lh*8];
            al[i] = *(const bf16x8*)&sAl[wm*64 + i*16 + lr][lh*8];
        }
        #pragma unroll
        for (int j = 0; j < 2; ++j) {
            bh[j] = *(const bf16x8*)&sBh[wn*32 + j*16 + lr][lh*8];
            bl[j] = *(const bf16x8*)&sBl[wn*32 + j*16 + lr][lh*8];
        }
        #pragma unroll
        for (int i = 0; i < 4; ++i)
            #pragma unroll
            for (int j = 0; j < 2; ++j) {
                acc[i][j] = MFMA(ah[i], bh[j], acc[i][j]);
                acc[i][j] = MFMA(ah[i], bl[j], acc[i][j]);
                acc[i][j] = MFMA(al[i], bh[j], acc[i][j]);
            }
        __syncthreads();
    }

    #pragma unroll
    for (int j = 0; j < 2; ++j) {
        const int n = n0 + wn*32 + j*16 + lr;
        const float bj = bo[n];
        #pragma unroll
        for (int i = 0; i < 4; ++i)
            #pragma unroll
            for (int r = 0; r < 4; ++r) {
                const int m = m0 + wm*64 + i*16 + lh*4 + r;
                out[(size_t)m * 1024 + n] = acc[i][j][r] + bj;
            }
    }
}

extern "C" void kernel_launch(void* const* d_in, const int* in_sizes, int n_in,
                              void* d_out, int out_size, void* d_ws, size_t ws_size,
                              hipStream_t stream)
{
    const float* x  = (const float*)d_in[0];
    const float* Wq = (const float*)d_in[1];
    const float* bq = (const float*)d_in[2];
    const float* Wk = (const float*)d_in[3];
    const float* bk = (const float*)d_in[4];
    const float* Wv = (const float*)d_in[5];
    const float* bv = (const float*)d_in[6];
    const float* Wo = (const float*)d_in[7];
    const float* bo = (const float*)d_in[8];

    float* out  = (float*)d_out;
    float* attn = out + (size_t)2 * S_ * D_;   // 4,194,304 floats in

    const size_t N = (size_t)4194304;          // elements per array
    u16* ws = (u16*)d_ws;                      // 8 arrays * 8 MB = 64 MB
    u16* q_hi = ws;          u16* q_lo = ws + N;
    u16* k_hi = ws + 2*N;    u16* k_lo = ws + 3*N;
    u16* v_hi = ws + 4*N;    u16* v_lo = ws + 5*N;
    u16* o_hi = ws + 6*N;    u16* o_lo = ws + 7*N;

    qkv_gemm<<<dim3(16, 32, 3), 256, 0, stream>>>(x, Wq, bq, Wk, bk, Wv, bv,
                                                  q_hi, q_lo, k_hi, k_lo, v_hi, v_lo);
    attn_fused<<<dim3(32, 32), 256, 0, stream>>>(q_hi, q_lo, k_hi, k_lo, v_hi, v_lo,
                                                 attn, o_hi, o_lo);
    o_gemm<<<dim3(16, 32), 256, 0, stream>>>(o_hi, o_lo, Wo, bo, out);
}